// Round 2
// baseline (252.751 us; speedup 1.0000x reference)
//
#include <hip/hip_runtime.h>

#define NBINS 15
#define NREP 8            // global accumulator replicas (one per XCD) to cut atomic contention
#define REP_STRIDE 16
#define WS_WORDS (NREP * REP_STRIDE + 16)   // 8*16 floats + counter word(s)

// ws layout: replica r at [r*16 .. r*16+14] = per-bin sum of (conf - correct)
//            word 128 = completion counter (unsigned)

__global__ void ece_init(float* __restrict__ ws) {
    int t = threadIdx.x;
    if (t < WS_WORDS) ws[t] = 0.0f;   // 0.0f bit pattern also zeroes the counter
}

__device__ __forceinline__ void ece_elem(float cv, int pr, int lb,
                                         float* hist_wave) {
    // bin k covers (k/15, (k+1)/15]  ->  k = ceil(cv*15) - 1 ; cv==0 -> no bin
    int b = (int)ceilf(cv * 15.0f) - 1;
    bool valid = (b >= 0) && (b < NBINS);
    float d = cv - ((pr == lb) ? 1.0f : 0.0f);
    d = valid ? d : 0.0f;
    b = valid ? b : 0;
    atomicAdd(hist_wave + b, d);   // ds_add_f32, branchless
}

__global__ __launch_bounds__(256) void ece_main(const float* __restrict__ conf,
                                                const int* __restrict__ pred,
                                                const int* __restrict__ lab,
                                                float* __restrict__ ws,
                                                unsigned* __restrict__ counter,
                                                float* __restrict__ out,
                                                int nvec, float inv_n, int nblocks) {
    __shared__ float hist[4][16];     // per-wave histogram, padded stride 16
    if (threadIdx.x < 64) ((float*)hist)[threadIdx.x] = 0.0f;
    __syncthreads();

    const float4* __restrict__ c4 = (const float4*)conf;
    const int4*   __restrict__ p4 = (const int4*)pred;
    const int4*   __restrict__ l4 = (const int4*)lab;

    int tid    = blockIdx.x * blockDim.x + threadIdx.x;
    int stride = gridDim.x * blockDim.x;
    int wave   = threadIdx.x >> 6;
    float* hw  = hist[wave];

    int i = tid;
    // Unrolled-by-4: 12 independent 16B loads in flight per iteration.
    for (; i + 3 * stride < nvec; i += 4 * stride) {
        float4 c0 = c4[i];
        float4 c1 = c4[i + stride];
        float4 c2 = c4[i + 2 * stride];
        float4 c3 = c4[i + 3 * stride];
        int4 p0 = p4[i];
        int4 p1 = p4[i + stride];
        int4 p2 = p4[i + 2 * stride];
        int4 p3 = p4[i + 3 * stride];
        int4 l0 = l4[i];
        int4 l1 = l4[i + stride];
        int4 l2 = l4[i + 2 * stride];
        int4 l3 = l4[i + 3 * stride];

        ece_elem(c0.x, p0.x, l0.x, hw); ece_elem(c0.y, p0.y, l0.y, hw);
        ece_elem(c0.z, p0.z, l0.z, hw); ece_elem(c0.w, p0.w, l0.w, hw);
        ece_elem(c1.x, p1.x, l1.x, hw); ece_elem(c1.y, p1.y, l1.y, hw);
        ece_elem(c1.z, p1.z, l1.z, hw); ece_elem(c1.w, p1.w, l1.w, hw);
        ece_elem(c2.x, p2.x, l2.x, hw); ece_elem(c2.y, p2.y, l2.y, hw);
        ece_elem(c2.z, p2.z, l2.z, hw); ece_elem(c2.w, p2.w, l2.w, hw);
        ece_elem(c3.x, p3.x, l3.x, hw); ece_elem(c3.y, p3.y, l3.y, hw);
        ece_elem(c3.z, p3.z, l3.z, hw); ece_elem(c3.w, p3.w, l3.w, hw);
    }
    // Tail (not executed for N=16777216 with grid 2048x256, kept for safety).
    for (; i < nvec; i += stride) {
        float4 c = c4[i];
        int4   p = p4[i];
        int4   l = l4[i];
        ece_elem(c.x, p.x, l.x, hw); ece_elem(c.y, p.y, l.y, hw);
        ece_elem(c.z, p.z, l.z, hw); ece_elem(c.w, p.w, l.w, hw);
    }
    __syncthreads();

    // Block-level: 15 lanes fold the 4 wave-histograms, one global atomic each.
    if (threadIdx.x < NBINS) {
        int k = threadIdx.x;
        float s = hist[0][k] + hist[1][k] + hist[2][k] + hist[3][k];
        atomicAdd(ws + (blockIdx.x & (NREP - 1)) * REP_STRIDE + k, s);
    }

    // Last-block finalize.
    __threadfence();
    __syncthreads();
    __shared__ unsigned rank;
    if (threadIdx.x == 0) rank = atomicAdd(counter, 1u);
    __syncthreads();
    if (rank == (unsigned)(nblocks - 1)) {
        float v = 0.0f;
        if (threadIdx.x < NBINS) {
            float s = 0.0f;
#pragma unroll
            for (int r = 0; r < NREP; ++r)
                s += atomicAdd(ws + r * REP_STRIDE + threadIdx.x, 0.0f);  // coherent read
            v = fabsf(s) * inv_n;
        }
#pragma unroll
        for (int m = 1; m < 64; m <<= 1) v += __shfl_xor(v, m, 64);
        if (threadIdx.x == 0) out[0] = v;
    }
}

extern "C" void kernel_launch(void* const* d_in, const int* in_sizes, int n_in,
                              void* d_out, int out_size, void* d_ws, size_t ws_size,
                              hipStream_t stream) {
    const float* conf = (const float*)d_in[0];
    const int*   pred = (const int*)d_in[1];
    const int*   lab  = (const int*)d_in[2];
    float*    ws      = (float*)d_ws;
    unsigned* counter = (unsigned*)(ws + NREP * REP_STRIDE);
    float*    out     = (float*)d_out;
    int n    = in_sizes[0];
    int nvec = n / 4;        // N = 16777216, divisible by 4

    const int nblocks = 2048;
    ece_init<<<1, 160, 0, stream>>>(ws);
    ece_main<<<nblocks, 256, 0, stream>>>(conf, pred, lab, ws, counter, out,
                                          nvec, 1.0f / (float)n, nblocks);
}